// Round 1
// baseline (152.921 us; speedup 1.0000x reference)
//
#include <hip/hip_runtime.h>
#include <cstdint>

#define FP8MAX 448.0f

typedef float f32x4 __attribute__((ext_vector_type(4)));
typedef int   i32x4 __attribute__((ext_vector_type(4)));

__device__ __forceinline__ void gload_lds16(const void* g, void* l) {
  __builtin_amdgcn_global_load_lds(
      (const __attribute__((address_space(1))) unsigned int*)g,
      (__attribute__((address_space(3))) unsigned int*)l,
      16, 0, 0);
}

// ---------- quantize x rows: H=2048 floats -> fp8 bytes + per-128-group inv_scale ----------
__global__ __launch_bounds__(256) void quant_x(const float* __restrict__ x,
                                               uint8_t* __restrict__ xq,
                                               float* __restrict__ sa) {
  const int m = blockIdx.x;
  const int t = threadIdx.x;
  const float* xr = x + (size_t)m * 2048;
  float4 v0 = ((const float4*)xr)[t * 2];
  float4 v1 = ((const float4*)xr)[t * 2 + 1];
  float amax = fmaxf(fmaxf(fmaxf(fabsf(v0.x), fabsf(v0.y)), fmaxf(fabsf(v0.z), fabsf(v0.w))),
                     fmaxf(fmaxf(fabsf(v1.x), fabsf(v1.y)), fmaxf(fabsf(v1.z), fabsf(v1.w))));
  // reduce over the 16 lanes that share a 128-elem group
  #pragma unroll
  for (int off = 1; off < 16; off <<= 1)
    amax = fmaxf(amax, __shfl_xor(amax, off));
  amax = fmaxf(amax, 1e-12f);
  float s   = FP8MAX / amax;   // same op order as reference
  float inv = 1.0f / s;
  if ((t & 15) == 0) sa[(size_t)m * 16 + (t >> 4)] = inv;
  float q[8] = {v0.x * s, v0.y * s, v0.z * s, v0.w * s,
                v1.x * s, v1.y * s, v1.z * s, v1.w * s};
  #pragma unroll
  for (int i = 0; i < 8; ++i) q[i] = fminf(fmaxf(q[i], -FP8MAX), FP8MAX);
  union { unsigned long long u; unsigned int w[2]; } pk;
  pk.w[0] = __builtin_amdgcn_cvt_pk_fp8_f32(q[0], q[1], 0, false);
  pk.w[0] = __builtin_amdgcn_cvt_pk_fp8_f32(q[2], q[3], pk.w[0], true);
  pk.w[1] = __builtin_amdgcn_cvt_pk_fp8_f32(q[4], q[5], 0, false);
  pk.w[1] = __builtin_amdgcn_cvt_pk_fp8_f32(q[6], q[7], pk.w[1], true);
  ((unsigned long long*)(xq + (size_t)m * 2048))[t] = pk.u;
}

// ---------- weight f32 -> fp8 (values are exactly fp8-representable; cast is exact) ----------
__global__ __launch_bounds__(256) void conv_w(const float* __restrict__ w,
                                              uint8_t* __restrict__ w8, int n8) {
  int i = blockIdx.x * 256 + threadIdx.x;
  if (i >= n8) return;
  float4 v0 = ((const float4*)w)[i * 2];
  float4 v1 = ((const float4*)w)[i * 2 + 1];
  union { unsigned long long u; unsigned int x[2]; } pk;
  pk.x[0] = __builtin_amdgcn_cvt_pk_fp8_f32(v0.x, v0.y, 0, false);
  pk.x[0] = __builtin_amdgcn_cvt_pk_fp8_f32(v0.z, v0.w, pk.x[0], true);
  pk.x[1] = __builtin_amdgcn_cvt_pk_fp8_f32(v1.x, v1.y, 0, false);
  pk.x[1] = __builtin_amdgcn_cvt_pk_fp8_f32(v1.z, v1.w, pk.x[1], true);
  ((unsigned long long*)w8)[i] = pk.u;
}

// ---------- block-scaled fp8 GEMM: out[M][N] = dequant(A[M][K]) @ dequant(B[N][K])^T + bias ----------
// BM=BN=BK=128, 256 threads = 4 waves (2x2), 64x64 per wave, mfma_f32_16x16x32_fp8_fp8.
__global__ __launch_bounds__(256, 2) void gemm_fp8(
    const uint8_t* __restrict__ A, const uint8_t* __restrict__ Bw,
    const float* __restrict__ sa, const float* __restrict__ sb,
    const float* __restrict__ bias, float* __restrict__ out,
    int M, int N, int K) {
  const int J = K >> 7;               // 16
  const int nbn = N >> 7;             // 16
  const int bn = blockIdx.x % nbn;
  const int bm = blockIdx.x / nbn;
  const int t = threadIdx.x;
  const int lane = t & 63;
  const int w = t >> 6;
  const int wm = (w >> 1) << 6;
  const int wn = (w & 1) << 6;
  const int r16 = lane & 15;
  const int kg = lane >> 4;

  __shared__ __align__(16) uint8_t lA[2][128 * 128];
  __shared__ __align__(16) uint8_t lB[2][128 * 128];
  __shared__ __align__(16) float sal[16 * 128];   // [j][row]

  const uint8_t* gA = A + (size_t)bm * 128 * K;
  const uint8_t* gB = Bw + (size_t)bn * 128 * K;

  // stage inv_scale slab for this block's 128 rows, transposed to [j][row]
  for (int i = t; i < 128 * 16; i += 256) {
    int row = i >> 4, j = i & 15;
    sal[j * 128 + row] = sa[((size_t)bm * 128 + row) * 16 + j];
  }

  const int srow = t >> 3;     // 0..31
  const int sseg = t & 7;      // 16B segment

  // prologue: stage K-tile 0 into buffer 0 (pre-swizzled global source, linear LDS dest)
  #pragma unroll
  for (int it = 0; it < 4; ++it) {
    int r = srow + it * 32;
    int ss = ((sseg ^ (r & 7)) << 4);
    gload_lds16(gA + (size_t)r * K + ss, &lA[0][r * 128 + sseg * 16]);
    gload_lds16(gB + (size_t)r * K + ss, &lB[0][r * 128 + sseg * 16]);
  }
  __syncthreads();

  f32x4 tot[4][4] = {};
  const f32x4 fz = {0.f, 0.f, 0.f, 0.f};

  int rowA[4], rowB[4];
  #pragma unroll
  for (int a = 0; a < 4; ++a) rowA[a] = wm + a * 16 + r16;
  #pragma unroll
  for (int b = 0; b < 4; ++b) rowB[b] = wn + b * 16 + r16;

  int cur = 0;
  const int KT = K >> 7;
  for (int kt = 0; kt < KT; ++kt) {
    if (kt + 1 < KT) {   // stage next tile into other buffer
      const uint8_t* gA2 = gA + (size_t)(kt + 1) * 128;
      const uint8_t* gB2 = gB + (size_t)(kt + 1) * 128;
      #pragma unroll
      for (int it = 0; it < 4; ++it) {
        int r = srow + it * 32;
        int ss = ((sseg ^ (r & 7)) << 4);
        gload_lds16(gA2 + (size_t)r * K + ss, &lA[cur ^ 1][r * 128 + sseg * 16]);
        gload_lds16(gB2 + (size_t)r * K + ss, &lB[cur ^ 1][r * 128 + sseg * 16]);
      }
    }
    // compute this K-tile (128) into part, then scaled-accumulate into tot
    f32x4 part[4][4];
    #pragma unroll
    for (int p = 0; p < 2; ++p) {
      i32x4 av[4], bv[4];
      #pragma unroll
      for (int a = 0; a < 4; ++a) {
        int off = (p * 64 + kg * 16) ^ ((rowA[a] & 7) << 4);
        av[a] = *(const i32x4*)&lA[cur][rowA[a] * 128 + off];
      }
      #pragma unroll
      for (int b = 0; b < 4; ++b) {
        int off = (p * 64 + kg * 16) ^ ((rowB[b] & 7) << 4);
        bv[b] = *(const i32x4*)&lB[cur][rowB[b] * 128 + off];
      }
      #pragma unroll
      for (int h = 0; h < 2; ++h) {
        #pragma unroll
        for (int a = 0; a < 4; ++a) {
          union { i32x4 v; long long l[2]; } ua; ua.v = av[a];
          long long aa = ua.l[h];
          #pragma unroll
          for (int b = 0; b < 4; ++b) {
            union { i32x4 v; long long l[2]; } ub; ub.v = bv[b];
            part[a][b] = __builtin_amdgcn_mfma_f32_16x16x32_fp8_fp8(
                aa, ub.l[h], (p == 0 && h == 0) ? fz : part[a][b], 0, 0, 0);
          }
        }
      }
    }
    float sbj = sb[bn * J + kt];
    #pragma unroll
    for (int a = 0; a < 4; ++a) {
      f32x4 sv = *(const f32x4*)&sal[kt * 128 + wm + a * 16 + kg * 4];
      f32x4 sc = sv * sbj;
      #pragma unroll
      for (int b = 0; b < 4; ++b)
        tot[a][b] += part[a][b] * sc;
    }
    __syncthreads();
    cur ^= 1;
  }

  // epilogue: add bias, store f32
  float bb4[4];
  #pragma unroll
  for (int b = 0; b < 4; ++b) bb4[b] = bias[bn * 128 + wn + b * 16 + r16];
  #pragma unroll
  for (int a = 0; a < 4; ++a) {
    int row0 = bm * 128 + wm + a * 16 + kg * 4;
    #pragma unroll
    for (int r = 0; r < 4; ++r) {
      float* orow = out + (size_t)(row0 + r) * N + bn * 128;
      #pragma unroll
      for (int b = 0; b < 4; ++b)
        orow[wn + b * 16 + r16] = tot[a][b][r] + bb4[b];
    }
  }
}

extern "C" void kernel_launch(void* const* d_in, const int* in_sizes, int n_in,
                              void* d_out, int out_size, void* d_ws, size_t ws_size,
                              hipStream_t stream) {
  const float* x    = (const float*)d_in[0];
  const float* wt   = (const float*)d_in[1];
  const float* wsc  = (const float*)d_in[2];
  const float* bias = (const float*)d_in[3];
  float* out = (float*)d_out;

  const int O = in_sizes[3];            // 2048
  const int H = in_sizes[1] / O;        // 2048
  const int M = in_sizes[0] / H;        // 16384

  uint8_t* xq = (uint8_t*)d_ws;                       // M*H bytes
  uint8_t* w8 = xq + (size_t)M * H;                   // O*H bytes
  float*   sa = (float*)(w8 + (size_t)O * H);         // M*(H/128) floats

  quant_x<<<M, 256, 0, stream>>>(x, xq, sa);
  int n8 = O * H / 8;
  conv_w<<<(n8 + 255) / 256, 256, 0, stream>>>(wt, w8, n8);
  int grid = (M / 128) * (O / 128);
  gemm_fp8<<<grid, 256, 0, stream>>>(xq, w8, sa, wsc, bias, out, M, O, H);
}

// Round 2
// 134.147 us; speedup vs baseline: 1.1400x; 1.1400x over previous
//
#include <hip/hip_runtime.h>
#include <cstdint>

#define FP8MAX 448.0f

typedef float f32x4 __attribute__((ext_vector_type(4)));
typedef int   i32x4 __attribute__((ext_vector_type(4)));
typedef int   i32x8 __attribute__((ext_vector_type(8)));

union frag8 { i32x8 v8; i32x4 v4[2]; };

__device__ __forceinline__ void gload_lds16(const void* g, void* l) {
  __builtin_amdgcn_global_load_lds(
      (const __attribute__((address_space(1))) unsigned int*)g,
      (__attribute__((address_space(3))) unsigned int*)l,
      16, 0, 0);
}

// ---------- quantize x rows: H=2048 floats -> fp8 bytes + per-128-group inv_scale ----------
__global__ __launch_bounds__(256) void quant_x(const float* __restrict__ x,
                                               uint8_t* __restrict__ xq,
                                               float* __restrict__ sa) {
  const int m = blockIdx.x;
  const int t = threadIdx.x;
  const float* xr = x + (size_t)m * 2048;
  float4 v0 = ((const float4*)xr)[t * 2];
  float4 v1 = ((const float4*)xr)[t * 2 + 1];
  float amax = fmaxf(fmaxf(fmaxf(fabsf(v0.x), fabsf(v0.y)), fmaxf(fabsf(v0.z), fabsf(v0.w))),
                     fmaxf(fmaxf(fabsf(v1.x), fabsf(v1.y)), fmaxf(fabsf(v1.z), fabsf(v1.w))));
  #pragma unroll
  for (int off = 1; off < 16; off <<= 1)
    amax = fmaxf(amax, __shfl_xor(amax, off));
  amax = fmaxf(amax, 1e-12f);
  float s   = FP8MAX / amax;   // same op order as reference
  float inv = 1.0f / s;
  if ((t & 15) == 0) sa[(size_t)m * 16 + (t >> 4)] = inv;
  float q[8] = {v0.x * s, v0.y * s, v0.z * s, v0.w * s,
                v1.x * s, v1.y * s, v1.z * s, v1.w * s};
  #pragma unroll
  for (int i = 0; i < 8; ++i) q[i] = fminf(fmaxf(q[i], -FP8MAX), FP8MAX);
  union { unsigned long long u; unsigned int w[2]; } pk;
  pk.w[0] = __builtin_amdgcn_cvt_pk_fp8_f32(q[0], q[1], 0, false);
  pk.w[0] = __builtin_amdgcn_cvt_pk_fp8_f32(q[2], q[3], pk.w[0], true);
  pk.w[1] = __builtin_amdgcn_cvt_pk_fp8_f32(q[4], q[5], 0, false);
  pk.w[1] = __builtin_amdgcn_cvt_pk_fp8_f32(q[6], q[7], pk.w[1], true);
  ((unsigned long long*)(xq + (size_t)m * 2048))[t] = pk.u;
}

// ---------- weight f32 -> fp8 (values are exactly fp8-representable; cast is exact) ----------
__global__ __launch_bounds__(256) void conv_w(const float* __restrict__ w,
                                              uint8_t* __restrict__ w8, int n8) {
  int i = blockIdx.x * 256 + threadIdx.x;
  if (i >= n8) return;
  float4 v0 = ((const float4*)w)[i * 2];
  float4 v1 = ((const float4*)w)[i * 2 + 1];
  union { unsigned long long u; unsigned int x[2]; } pk;
  pk.x[0] = __builtin_amdgcn_cvt_pk_fp8_f32(v0.x, v0.y, 0, false);
  pk.x[0] = __builtin_amdgcn_cvt_pk_fp8_f32(v0.z, v0.w, pk.x[0], true);
  pk.x[1] = __builtin_amdgcn_cvt_pk_fp8_f32(v1.x, v1.y, 0, false);
  pk.x[1] = __builtin_amdgcn_cvt_pk_fp8_f32(v1.z, v1.w, pk.x[1], true);
  ((unsigned long long*)w8)[i] = pk.u;
}

// ---------- block-scaled fp8 GEMM via MX MFMA (unit e8m0 scales) ----------
// BM=BN=BK=128, 256 threads = 4 waves (2x2), 64x64 per wave,
// mfma_scale_f32_16x16x128_f8f6f4: one instruction per K-group per 16x16 sub-tile.
__global__ __launch_bounds__(256, 2) void gemm_fp8(
    const uint8_t* __restrict__ A, const uint8_t* __restrict__ Bw,
    const float* __restrict__ sa, const float* __restrict__ sb,
    const float* __restrict__ bias, float* __restrict__ out,
    int M, int N, int K) {
  const int J = K >> 7;               // 16
  const int nbn = N >> 7;             // 16
  // T1: XCD-aware chunked swizzle (grid must be %8==0; 2048 is)
  int bid = blockIdx.x;
  int nwg = gridDim.x;
  if ((nwg & 7) == 0) {
    int cpx = nwg >> 3;
    bid = (bid & 7) * cpx + (bid >> 3);
  }
  const int bn = bid % nbn;
  const int bm = bid / nbn;
  const int t = threadIdx.x;
  const int lane = t & 63;
  const int w = t >> 6;
  const int wm = (w >> 1) << 6;
  const int wn = (w & 1) << 6;
  const int r16 = lane & 15;
  const int kg = lane >> 4;

  __shared__ __align__(16) uint8_t lA[2][128 * 128];
  __shared__ __align__(16) uint8_t lB[2][128 * 128];
  __shared__ __align__(16) float sal[16 * 132];   // [j][row], stride 132 kills bank conflicts

  const uint8_t* gA = A + (size_t)bm * 128 * K;
  const uint8_t* gB = Bw + (size_t)bn * 128 * K;

  // stage inv_scale slab for this block's 128 rows, transposed to [j][row]
  for (int i = t; i < 128 * 16; i += 256) {
    int row = i >> 4, j = i & 15;
    sal[j * 132 + row] = sa[((size_t)bm * 128 + row) * 16 + j];
  }

  const int srow = t >> 3;     // 0..31
  const int sseg = t & 7;      // 16B segment

  // prologue: stage K-tile 0 into buffer 0 (pre-swizzled global source, linear LDS dest)
  #pragma unroll
  for (int it = 0; it < 4; ++it) {
    int r = srow + it * 32;
    int ss = ((sseg ^ (r & 7)) << 4);
    gload_lds16(gA + (size_t)r * K + ss, &lA[0][r * 128 + sseg * 16]);
    gload_lds16(gB + (size_t)r * K + ss, &lB[0][r * 128 + sseg * 16]);
  }
  __syncthreads();

  f32x4 tot[4][4] = {};
  const f32x4 fz = {0.f, 0.f, 0.f, 0.f};

  int rowA[4], rowB[4];
  #pragma unroll
  for (int a = 0; a < 4; ++a) rowA[a] = wm + a * 16 + r16;
  #pragma unroll
  for (int b = 0; b < 4; ++b) rowB[b] = wn + b * 16 + r16;

  int cur = 0;
  const int KT = K >> 7;
  for (int kt = 0; kt < KT; ++kt) {
    if (kt + 1 < KT) {   // stage next tile into other buffer
      const uint8_t* gA2 = gA + (size_t)(kt + 1) * 128;
      const uint8_t* gB2 = gB + (size_t)(kt + 1) * 128;
      #pragma unroll
      for (int it = 0; it < 4; ++it) {
        int r = srow + it * 32;
        int ss = ((sseg ^ (r & 7)) << 4);
        gload_lds16(gA2 + (size_t)r * K + ss, &lA[cur ^ 1][r * 128 + sseg * 16]);
        gload_lds16(gB2 + (size_t)r * K + ss, &lB[cur ^ 1][r * 128 + sseg * 16]);
      }
    }
    // load fragments: each lane reads k-bytes [kg*32, kg*32+32) of its row
    frag8 av[4], bv[4];
    #pragma unroll
    for (int a = 0; a < 4; ++a) {
      const int swz = (rowA[a] & 7) << 4;
      const uint8_t* base = &lA[cur][rowA[a] * 128];
      av[a].v4[0] = *(const i32x4*)(base + ((kg * 32) ^ swz));
      av[a].v4[1] = *(const i32x4*)(base + ((kg * 32 + 16) ^ swz));
    }
    #pragma unroll
    for (int b = 0; b < 4; ++b) {
      const int swz = (rowB[b] & 7) << 4;
      const uint8_t* base = &lB[cur][rowB[b] * 128];
      bv[b].v4[0] = *(const i32x4*)(base + ((kg * 32) ^ swz));
      bv[b].v4[1] = *(const i32x4*)(base + ((kg * 32 + 16) ^ swz));
    }
    const float sbj = sb[bn * J + kt];
    #pragma unroll
    for (int a = 0; a < 4; ++a) {
      f32x4 sc = *(const f32x4*)&sal[kt * 132 + wm + a * 16 + kg * 4];
      sc *= sbj;
      #pragma unroll
      for (int b = 0; b < 4; ++b) {
        f32x4 part = __builtin_amdgcn_mfma_scale_f32_16x16x128_f8f6f4(
            av[a].v8, bv[b].v8, fz, 0, 0, 0, 0x7f7f7f7f, 0, 0x7f7f7f7f);
        tot[a][b] += part * sc;
      }
    }
    __syncthreads();
    cur ^= 1;
  }

  // epilogue: add bias, store f32 (C/D layout: col=lane&15, row=kg*4+reg)
  float bb4[4];
  #pragma unroll
  for (int b = 0; b < 4; ++b) bb4[b] = bias[bn * 128 + wn + b * 16 + r16];
  #pragma unroll
  for (int a = 0; a < 4; ++a) {
    int row0 = bm * 128 + wm + a * 16 + kg * 4;
    #pragma unroll
    for (int r = 0; r < 4; ++r) {
      float* orow = out + (size_t)(row0 + r) * N + bn * 128;
      #pragma unroll
      for (int b = 0; b < 4; ++b)
        orow[wn + b * 16 + r16] = tot[a][b][r] + bb4[b];
    }
  }
}

extern "C" void kernel_launch(void* const* d_in, const int* in_sizes, int n_in,
                              void* d_out, int out_size, void* d_ws, size_t ws_size,
                              hipStream_t stream) {
  const float* x    = (const float*)d_in[0];
  const float* wt   = (const float*)d_in[1];
  const float* wsc  = (const float*)d_in[2];
  const float* bias = (const float*)d_in[3];
  float* out = (float*)d_out;

  const int O = in_sizes[3];            // 2048
  const int H = in_sizes[1] / O;        // 2048
  const int M = in_sizes[0] / H;        // 16384

  uint8_t* xq = (uint8_t*)d_ws;                       // M*H bytes
  uint8_t* w8 = xq + (size_t)M * H;                   // O*H bytes
  float*   sa = (float*)(w8 + (size_t)O * H);         // M*(H/128) floats

  quant_x<<<M, 256, 0, stream>>>(x, xq, sa);
  int n8 = O * H / 8;
  conv_w<<<(n8 + 255) / 256, 256, 0, stream>>>(wt, w8, n8);
  int grid = (M / 128) * (O / 128);
  gemm_fp8<<<grid, 256, 0, stream>>>(xq, w8, sa, wsc, bias, out, M, O, H);
}